// Round 9
// baseline (263.405 us; speedup 1.0000x reference)
//
#include <hip/hip_runtime.h>
#include <hip/hip_bf16.h>

#define N 2048
#define B 16
#define LOG2E 1.44269504088896340736f

typedef float v4f __attribute__((ext_vector_type(4)));

// Kernel 1: asum2[b,i] = LOG2E * sum_k |s[b,i] - s[b,k]|
__global__ __launch_bounds__(256) void asum_kernel(const float* __restrict__ s,
                                                   float* __restrict__ asum2) {
    const int b = blockIdx.y;
    const int chunk = blockIdx.x;

    __shared__ float row[N];
    __shared__ float partial[256];
    const v4f* g4 = (const v4f*)(s + b * N);
    v4f* r4 = (v4f*)row;
    r4[threadIdx.x] = g4[threadIdx.x];
    r4[threadIdx.x + 256] = g4[threadIdx.x + 256];
    __syncthreads();

    const int il = threadIdx.x & 127;
    const int half = threadIdx.x >> 7;   // wave-uniform
    const int i = chunk * 128 + il;
    const float si = row[i];
    const v4f* row4 = (const v4f*)(row + half * (N / 2));
    float acc = 0.0f;
#pragma unroll 4
    for (int k = 0; k < N / 8; ++k) {
        v4f rv = row4[k];
        acc += fabsf(si - rv.x) + fabsf(si - rv.y) +
               fabsf(si - rv.z) + fabsf(si - rv.w);
    }
    partial[threadIdx.x] = acc;
    __syncthreads();
    if (threadIdx.x < 128)
        asum2[b * N + i] = LOG2E * (partial[threadIdx.x] + partial[threadIdx.x + 128]);
}

// Kernel 2: 16 rows per block; each wave processes FOUR independent rows
// (j = base+wave+{0,4,8,12}) interleaved for ILP. Within-lane reductions are
// pairwise trees (depth 5, not 31). s/asum2 staged in LDS once per 16 rows.
// grid = (N/16, B), block = 256.
__global__ __launch_bounds__(256) void softmax_rows(const float* __restrict__ s,
                                                    const float* __restrict__ asum2,
                                                    float* __restrict__ out) {
    __shared__ float ls[N];   // s * LOG2E
    __shared__ float la[N];   // asum2 (LOG2E already folded)

    const int t = threadIdx.x;
    const int lane = t & 63;
    const int wave = t >> 6;
    const int b = blockIdx.y;
    const int j0 = blockIdx.x * 16 + wave;

    {
        const v4f* g4 = (const v4f*)(s + (size_t)b * N);
        const v4f* ga4 = (const v4f*)(asum2 + (size_t)b * N);
        v4f* l4 = (v4f*)ls;
        v4f* m4 = (v4f*)la;
        v4f s0 = g4[t], s1 = g4[t + 256];
        v4f a0 = ga4[t], a1 = ga4[t + 256];
        s0 *= LOG2E; s1 *= LOG2E;
        l4[t] = s0; l4[t + 256] = s1;
        m4[t] = a0; m4[t + 256] = a1;
    }
    __syncthreads();

    float c[4];
#pragma unroll
    for (int r = 0; r < 4; ++r)
        c[r] = (float)(N - 1 - 2 * (j0 + 4 * r));

    const v4f* ls4 = (const v4f*)ls;
    const v4f* la4 = (const v4f*)la;

    float v[4][32];
#pragma unroll
    for (int ch = 0; ch < 8; ++ch) {
        v4f sv = ls4[ch * 64 + lane];
        v4f av = la4[ch * 64 + lane];
#pragma unroll
        for (int r = 0; r < 4; ++r) {
            v[r][ch * 4 + 0] = sv.x * c[r] - av.x;
            v[r][ch * 4 + 1] = sv.y * c[r] - av.y;
            v[r][ch * 4 + 2] = sv.z * c[r] - av.z;
            v[r][ch * 4 + 3] = sv.w * c[r] - av.w;
        }
    }

    // tree max within lane (depth 5), 4 rows interleaved
    float m[4];
#pragma unroll
    for (int r = 0; r < 4; ++r) {
        float t16[16];
#pragma unroll
        for (int i = 0; i < 16; ++i) t16[i] = fmaxf(v[r][i], v[r][i + 16]);
#pragma unroll
        for (int i = 0; i < 8; ++i) t16[i] = fmaxf(t16[i], t16[i + 8]);
#pragma unroll
        for (int i = 0; i < 4; ++i) t16[i] = fmaxf(t16[i], t16[i + 4]);
        m[r] = fmaxf(fmaxf(t16[0], t16[1]), fmaxf(t16[2], t16[3]));
    }
#pragma unroll
    for (int off = 32; off >= 1; off >>= 1) {
#pragma unroll
        for (int r = 0; r < 4; ++r)
            m[r] = fmaxf(m[r], __shfl_xor(m[r], off));
    }

    // exp2 + tree sum (4 partial accumulators per row), rows interleaved
    float sum[4];
#pragma unroll
    for (int r = 0; r < 4; ++r) {
        float p0 = 0.0f, p1 = 0.0f, p2 = 0.0f, p3 = 0.0f;
#pragma unroll
        for (int i = 0; i < 32; i += 4) {
            v[r][i + 0] = __builtin_amdgcn_exp2f(v[r][i + 0] - m[r]); p0 += v[r][i + 0];
            v[r][i + 1] = __builtin_amdgcn_exp2f(v[r][i + 1] - m[r]); p1 += v[r][i + 1];
            v[r][i + 2] = __builtin_amdgcn_exp2f(v[r][i + 2] - m[r]); p2 += v[r][i + 2];
            v[r][i + 3] = __builtin_amdgcn_exp2f(v[r][i + 3] - m[r]); p3 += v[r][i + 3];
        }
        sum[r] = (p0 + p1) + (p2 + p3);
    }
#pragma unroll
    for (int off = 32; off >= 1; off >>= 1) {
#pragma unroll
        for (int r = 0; r < 4; ++r)
            sum[r] += __shfl_xor(sum[r], off);
    }

#pragma unroll
    for (int r = 0; r < 4; ++r) {
        const float rz = 1.0f / sum[r];
        v4f* o4 = (v4f*)(out + ((size_t)b * N + (j0 + 4 * r)) * N);
#pragma unroll
        for (int ch = 0; ch < 8; ++ch) {
            v4f o;
            o.x = v[r][ch * 4 + 0] * rz;
            o.y = v[r][ch * 4 + 1] * rz;
            o.z = v[r][ch * 4 + 2] * rz;
            o.w = v[r][ch * 4 + 3] * rz;
            o4[ch * 64 + lane] = o;
        }
    }
}

extern "C" void kernel_launch(void* const* d_in, const int* in_sizes, int n_in,
                              void* d_out, int out_size, void* d_ws, size_t ws_size,
                              hipStream_t stream) {
    const float* scores = (const float*)d_in[0];
    float* out = (float*)d_out;
    float* asum2 = (float*)d_ws;   // B*N*4 = 128 KB

    dim3 g1(N / 128, B);
    asum_kernel<<<g1, 256, 0, stream>>>(scores, asum2);

    dim3 g2(N / 16, B);
    softmax_rows<<<g2, 256, 0, stream>>>(scores, asum2, out);
}